// Round 3
// baseline (214.594 us; speedup 1.0000x reference)
//
#include <hip/hip_runtime.h>
#include <hip/hip_bf16.h>
#include <stdint.h>

#define N_PTS 262144
#define KOFF 27
#define CIN 64
#define COUT 64
#define EPS 1e-5f

typedef __attribute__((ext_vector_type(8))) short short8;
typedef __attribute__((ext_vector_type(4))) float f32x4;
typedef __attribute__((ext_vector_type(4))) unsigned short ushort4v;

static __device__ __forceinline__ unsigned short f32_to_bf16(float f) {
    union { float f; unsigned int u; } v; v.f = f;
    unsigned int u = v.u;
    unsigned int rounded = u + 0x7FFF + ((u >> 16) & 1);
    return (unsigned short)(rounded >> 16);
}

// ---- P0: pack weight [27][64][64] f32 -> bf16 MFMA B-fragment order ----
// pw[k][s][t][lane][e]: B[k_local=(lane>>4)*8+e][col=lane&15], cin=s*32+k_local, cout=t*16+col
__global__ void k_packW(const float* __restrict__ w, unsigned short* __restrict__ pw) {
    int tid = blockIdx.x * blockDim.x + threadIdx.x;
    if (tid >= KOFF * 4096) return;
    int e = tid & 7;
    int l = (tid >> 3) & 63;
    int t = (tid >> 9) & 3;
    int s = (tid >> 11) & 1;
    int k = tid >> 12;
    int cin  = s * 32 + (l >> 4) * 8 + e;
    int cout = t * 16 + (l & 15);
    pw[tid] = f32_to_bf16(w[(k * CIN + cin) * COUT + cout]);
}

// ---- P1: features f32 -> bf16, with zero pad row at index N ----
__global__ void k_feat2bf16(const float* __restrict__ feat, unsigned short* __restrict__ out) {
    int gid = blockIdx.x * blockDim.x + threadIdx.x;
    const int total4 = (N_PTS + 1) * CIN / 4;
    if (gid >= total4) return;
    int base = gid * 4;
    ushort4v o;
    if (base < N_PTS * CIN) {
        f32x4 f = *reinterpret_cast<const f32x4*>(feat + base);
        o[0] = f32_to_bf16(f[0]); o[1] = f32_to_bf16(f[1]);
        o[2] = f32_to_bf16(f[2]); o[3] = f32_to_bf16(f[3]);
    } else {
        o[0] = 0; o[1] = 0; o[2] = 0; o[3] = 0;
    }
    *reinterpret_cast<ushort4v*>(out + base) = o;
}

// ---- M: gather + MFMA GEMM, BARRIER-FREE k-loop ----
// 256 thr = 4 waves, 128 rows/block (32 rows/wave via two 16-row subtiles).
// B fragments read directly from global (L2-resident, coalesced) - no LDS, no barriers.
__global__ __launch_bounds__(256) void k_conv(
    const unsigned short* __restrict__ feat,   // (N+1) x 64 bf16
    const int* __restrict__ nbr,               // 27 x N
    const unsigned short* __restrict__ pw,     // packed weights (bf16 frag order)
    float* __restrict__ conv_out,              // N x 64 (pre-BN)
    float* __restrict__ partials)              // nblocks x 128 (sum | sumsq)
{
    __shared__ float s_sum[64], s_sq[64];

    const int tid = threadIdx.x;
    const int l  = tid & 63;
    const int w  = tid >> 6;
    const int lr = l & 15;      // A row within 16 / C col within 16
    const int lg = l >> 4;      // k-group / C row group
    const int rowbase = blockIdx.x * 128 + w * 32;
    const int r0 = rowbase + lr;
    const int r1 = r0 + 16;
    const int lane_cin = lg * 8;

    if (tid < 64) { s_sum[tid] = 0.f; s_sq[tid] = 0.f; }

    f32x4 acc[2][4] = {};
    const short8* pwv = reinterpret_cast<const short8*>(pw);

    // prologue: idx[0..1], A[0]
    int i0  = nbr[r0];
    int i1  = nbr[r1];
    int i0n = nbr[N_PTS + r0];
    int i1n = nbr[N_PTS + r1];

    const short8* f0 = reinterpret_cast<const short8*>(feat + i0 * 64 + lane_cin);
    const short8* f1 = reinterpret_cast<const short8*>(feat + i1 * 64 + lane_cin);
    short8 a00 = f0[0], a01 = f0[4], a10 = f1[0], a11 = f1[4];

    for (int k = 0; k < KOFF - 1; ++k) {
        // B for this k: 8 coalesced short8 loads (L2-hit), issued FIRST so the
        // MFMA's vmcnt wait on B does not drain the younger A-prefetch gathers.
        const short8* bb = pwv + k * 512 + l;
        short8 b0 = bb[0];
        short8 b1 = bb[64];
        short8 b2 = bb[128];
        short8 b3 = bb[192];
        short8 b4 = bb[256];
        short8 b5 = bb[320];
        short8 b6 = bb[384];
        short8 b7 = bb[448];

        // prefetch A[k+1] (random gathers: get the whole MFMA phase + next B
        // loads as latency cover, never drained early)
        const short8* g0 = reinterpret_cast<const short8*>(feat + i0n * 64 + lane_cin);
        const short8* g1 = reinterpret_cast<const short8*>(feat + i1n * 64 + lane_cin);
        short8 n00 = g0[0], n01 = g0[4], n10 = g1[0], n11 = g1[4];

        // idx[k+2] (clamped; redundant last loads are harmless)
        const int k2 = (k + 2 < KOFF) ? (k + 2) : (KOFF - 1);
        i0n = nbr[k2 * N_PTS + r0];
        i1n = nbr[k2 * N_PTS + r1];

        // 16 MFMA: s=0 -> b0..b3 with a00/a10, s=1 -> b4..b7 with a01/a11
        acc[0][0] = __builtin_amdgcn_mfma_f32_16x16x32_bf16(a00, b0, acc[0][0], 0, 0, 0);
        acc[1][0] = __builtin_amdgcn_mfma_f32_16x16x32_bf16(a10, b0, acc[1][0], 0, 0, 0);
        acc[0][1] = __builtin_amdgcn_mfma_f32_16x16x32_bf16(a00, b1, acc[0][1], 0, 0, 0);
        acc[1][1] = __builtin_amdgcn_mfma_f32_16x16x32_bf16(a10, b1, acc[1][1], 0, 0, 0);
        acc[0][2] = __builtin_amdgcn_mfma_f32_16x16x32_bf16(a00, b2, acc[0][2], 0, 0, 0);
        acc[1][2] = __builtin_amdgcn_mfma_f32_16x16x32_bf16(a10, b2, acc[1][2], 0, 0, 0);
        acc[0][3] = __builtin_amdgcn_mfma_f32_16x16x32_bf16(a00, b3, acc[0][3], 0, 0, 0);
        acc[1][3] = __builtin_amdgcn_mfma_f32_16x16x32_bf16(a10, b3, acc[1][3], 0, 0, 0);
        acc[0][0] = __builtin_amdgcn_mfma_f32_16x16x32_bf16(a01, b4, acc[0][0], 0, 0, 0);
        acc[1][0] = __builtin_amdgcn_mfma_f32_16x16x32_bf16(a11, b4, acc[1][0], 0, 0, 0);
        acc[0][1] = __builtin_amdgcn_mfma_f32_16x16x32_bf16(a01, b5, acc[0][1], 0, 0, 0);
        acc[1][1] = __builtin_amdgcn_mfma_f32_16x16x32_bf16(a11, b5, acc[1][1], 0, 0, 0);
        acc[0][2] = __builtin_amdgcn_mfma_f32_16x16x32_bf16(a01, b6, acc[0][2], 0, 0, 0);
        acc[1][2] = __builtin_amdgcn_mfma_f32_16x16x32_bf16(a11, b6, acc[1][2], 0, 0, 0);
        acc[0][3] = __builtin_amdgcn_mfma_f32_16x16x32_bf16(a01, b7, acc[0][3], 0, 0, 0);
        acc[1][3] = __builtin_amdgcn_mfma_f32_16x16x32_bf16(a11, b7, acc[1][3], 0, 0, 0);

        a00 = n00; a01 = n01; a10 = n10; a11 = n11;
    }

    {   // peeled last iteration (k = KOFF-1): no prefetch
        const short8* bb = pwv + (KOFF - 1) * 512 + l;
        short8 b0 = bb[0];
        short8 b1 = bb[64];
        short8 b2 = bb[128];
        short8 b3 = bb[192];
        short8 b4 = bb[256];
        short8 b5 = bb[320];
        short8 b6 = bb[384];
        short8 b7 = bb[448];
        acc[0][0] = __builtin_amdgcn_mfma_f32_16x16x32_bf16(a00, b0, acc[0][0], 0, 0, 0);
        acc[1][0] = __builtin_amdgcn_mfma_f32_16x16x32_bf16(a10, b0, acc[1][0], 0, 0, 0);
        acc[0][1] = __builtin_amdgcn_mfma_f32_16x16x32_bf16(a00, b1, acc[0][1], 0, 0, 0);
        acc[1][1] = __builtin_amdgcn_mfma_f32_16x16x32_bf16(a10, b1, acc[1][1], 0, 0, 0);
        acc[0][2] = __builtin_amdgcn_mfma_f32_16x16x32_bf16(a00, b2, acc[0][2], 0, 0, 0);
        acc[1][2] = __builtin_amdgcn_mfma_f32_16x16x32_bf16(a10, b2, acc[1][2], 0, 0, 0);
        acc[0][3] = __builtin_amdgcn_mfma_f32_16x16x32_bf16(a00, b3, acc[0][3], 0, 0, 0);
        acc[1][3] = __builtin_amdgcn_mfma_f32_16x16x32_bf16(a10, b3, acc[1][3], 0, 0, 0);
        acc[0][0] = __builtin_amdgcn_mfma_f32_16x16x32_bf16(a01, b4, acc[0][0], 0, 0, 0);
        acc[1][0] = __builtin_amdgcn_mfma_f32_16x16x32_bf16(a11, b4, acc[1][0], 0, 0, 0);
        acc[0][1] = __builtin_amdgcn_mfma_f32_16x16x32_bf16(a01, b5, acc[0][1], 0, 0, 0);
        acc[1][1] = __builtin_amdgcn_mfma_f32_16x16x32_bf16(a11, b5, acc[1][1], 0, 0, 0);
        acc[0][2] = __builtin_amdgcn_mfma_f32_16x16x32_bf16(a01, b6, acc[0][2], 0, 0, 0);
        acc[1][2] = __builtin_amdgcn_mfma_f32_16x16x32_bf16(a11, b6, acc[1][2], 0, 0, 0);
        acc[0][3] = __builtin_amdgcn_mfma_f32_16x16x32_bf16(a01, b7, acc[0][3], 0, 0, 0);
        acc[1][3] = __builtin_amdgcn_mfma_f32_16x16x32_bf16(a11, b7, acc[1][3], 0, 0, 0);
    }

    // ---- epilogue: store conv (f32) + per-channel partial stats ----
    const int orow_base = rowbase + lg * 4;   // C row = lg*4 + e (+ m*16)
    #pragma unroll
    for (int t = 0; t < 4; ++t) {
        const int c = t * 16 + lr;            // C col = lane&15
        float psum = 0.f, psq = 0.f;
        #pragma unroll
        for (int m = 0; m < 2; ++m) {
            #pragma unroll
            for (int e = 0; e < 4; ++e) {
                float v = acc[m][t][e];
                conv_out[(orow_base + m * 16 + e) * 64 + c] = v;
                psum += v; psq += v * v;
            }
        }
        atomicAdd(&s_sum[c], psum);
        atomicAdd(&s_sq[c], psq);
    }
    __syncthreads();
    if (tid < 64) {
        partials[blockIdx.x * 128 + tid]      = s_sum[tid];
        partials[blockIdx.x * 128 + 64 + tid] = s_sq[tid];
    }
}

// ---- S: reduce partials -> scale/shift per channel ----
__global__ void k_stats(const float* __restrict__ partials,
                        const float* __restrict__ gamma,
                        const float* __restrict__ beta,
                        float* __restrict__ ss, int nblocks) {
    __shared__ float s_red[2];
    const int c = blockIdx.x;
    const int tid = threadIdx.x;
    if (tid < 2) s_red[tid] = 0.f;
    __syncthreads();
    float sum = 0.f, sq = 0.f;
    for (int b = tid; b < nblocks; b += blockDim.x) {
        sum += partials[b * 128 + c];
        sq  += partials[b * 128 + 64 + c];
    }
    #pragma unroll
    for (int off = 32; off > 0; off >>= 1) {
        sum += __shfl_down(sum, off, 64);
        sq  += __shfl_down(sq,  off, 64);
    }
    if ((tid & 63) == 0) { atomicAdd(&s_red[0], sum); atomicAdd(&s_red[1], sq); }
    __syncthreads();
    if (tid == 0) {
        float mean  = s_red[0] / (float)N_PTS;
        float var   = s_red[1] / (float)N_PTS - mean * mean;
        float scale = gamma[c] * rsqrtf(var + EPS);
        ss[c]      = scale;
        ss[64 + c] = beta[c] - mean * scale;
    }
}

// ---- F: in-place BN affine + ReLU on d_out ----
__global__ void k_bnrelu(float* __restrict__ out, const float* __restrict__ ss) {
    int gid = blockIdx.x * blockDim.x + threadIdx.x;   // N*64/4 threads
    int base = gid * 4;
    int c0 = base & 63;
    f32x4 v  = *reinterpret_cast<f32x4*>(out + base);
    f32x4 sc = *reinterpret_cast<const f32x4*>(ss + c0);
    f32x4 sh = *reinterpret_cast<const f32x4*>(ss + 64 + c0);
    f32x4 r;
    #pragma unroll
    for (int j = 0; j < 4; ++j) r[j] = fmaxf(v[j] * sc[j] + sh[j], 0.f);
    *reinterpret_cast<f32x4*>(out + base) = r;
}

extern "C" void kernel_launch(void* const* d_in, const int* in_sizes, int n_in,
                              void* d_out, int out_size, void* d_ws, size_t ws_size,
                              hipStream_t stream) {
    const float* features = (const float*)d_in[0];
    const int*   nbr      = (const int*)d_in[1];
    const float* weight   = (const float*)d_in[2];
    const float* gamma    = (const float*)d_in[3];
    const float* beta     = (const float*)d_in[4];
    float* out = (float*)d_out;
    char* ws = (char*)d_ws;

    const size_t off_feat = 0;                                   // (N+1)*64 bf16
    const size_t off_pw   = 33554560;                            // 27*4096 bf16
    const size_t off_part = off_pw + 221184;                     // 2048*128 f32
    const size_t off_ss   = off_part + 1048576;                  // 128 f32
    unsigned short* feat16   = (unsigned short*)(ws + off_feat);
    unsigned short* pw       = (unsigned short*)(ws + off_pw);
    float*          partials = (float*)(ws + off_part);
    float*          ss       = (float*)(ws + off_ss);

    const int nblocks = N_PTS / 128;   // 2048

    k_packW<<<(KOFF * 4096 + 255) / 256, 256, 0, stream>>>(weight, pw);
    k_feat2bf16<<<((N_PTS + 1) * CIN / 4 + 255) / 256, 256, 0, stream>>>(features, feat16);
    k_conv<<<nblocks, 256, 0, stream>>>(feat16, nbr, pw, out, partials);
    k_stats<<<64, 256, 0, stream>>>(partials, gamma, beta, ss, nblocks);
    k_bnrelu<<<N_PTS * COUT / 4 / 256, 256, 0, stream>>>(out, ss);
}

// Round 4
// 198.776 us; speedup vs baseline: 1.0796x; 1.0796x over previous
//
#include <hip/hip_runtime.h>
#include <hip/hip_bf16.h>
#include <stdint.h>

#define N_PTS 262144
#define KOFF 27
#define CIN 64
#define COUT 64
#define EPS 1e-5f

typedef __attribute__((ext_vector_type(8))) short short8;
typedef __attribute__((ext_vector_type(4))) float f32x4;
typedef __attribute__((ext_vector_type(4))) unsigned short ushort4v;

typedef __attribute__((address_space(3))) unsigned int lds_u32;
typedef __attribute__((address_space(1))) const unsigned int glb_u32;
#define GLDS16(g, s) __builtin_amdgcn_global_load_lds((glb_u32*)(g), (lds_u32*)(s), 16, 0, 0)

static __device__ __forceinline__ unsigned short f32_to_bf16(float f) {
    union { float f; unsigned int u; } v; v.f = f;
    unsigned int u = v.u;
    unsigned int rounded = u + 0x7FFF + ((u >> 16) & 1);
    return (unsigned short)(rounded >> 16);
}

// ---- P0: pack weight [27][64][64] f32 -> bf16 MFMA B-fragment order ----
// pw[k][s][t][lane][e]: B[k_local=(lane>>4)*8+e][col=lane&15], cin=s*32+k_local, cout=t*16+col
__global__ void k_packW(const float* __restrict__ w, unsigned short* __restrict__ pw) {
    int tid = blockIdx.x * blockDim.x + threadIdx.x;
    if (tid >= KOFF * 4096) return;
    int e = tid & 7;
    int l = (tid >> 3) & 63;
    int t = (tid >> 9) & 3;
    int s = (tid >> 11) & 1;
    int k = tid >> 12;
    int cin  = s * 32 + (l >> 4) * 8 + e;
    int cout = t * 16 + (l & 15);
    pw[tid] = f32_to_bf16(w[(k * CIN + cin) * COUT + cout]);
}

// ---- P1: features f32 -> bf16, with zero pad row at index N ----
__global__ void k_feat2bf16(const float* __restrict__ feat, unsigned short* __restrict__ out) {
    int gid = blockIdx.x * blockDim.x + threadIdx.x;
    const int total4 = (N_PTS + 1) * CIN / 4;
    if (gid >= total4) return;
    int base = gid * 4;
    ushort4v o;
    if (base < N_PTS * CIN) {
        f32x4 f = *reinterpret_cast<const f32x4*>(feat + base);
        o[0] = f32_to_bf16(f[0]); o[1] = f32_to_bf16(f[1]);
        o[2] = f32_to_bf16(f[2]); o[3] = f32_to_bf16(f[3]);
    } else {
        o[0] = 0; o[1] = 0; o[2] = 0; o[3] = 0;
    }
    *reinterpret_cast<ushort4v*>(out + base) = o;
}

// ---- M: gather + MFMA GEMM, counted-vmcnt pipeline ----
// 256 thr = 4 waves, 128 rows/block (32 rows/wave via two 16-row subtiles).
// B: global_load_lds into triple-buffered LDS (quarter per wave), read via ds_read
//    -> B never forces a vmcnt drain of the A-gathers.
// A: register gathers issued 2 iterations ahead; idx loads 4 ahead (volatile: keeps
//    the per-iter vmcnt op count exactly 8 so the hand-counted wait is exact).
// Per iter: raw s_barrier (no compiler vmcnt(0) drain) + asm s_waitcnt vmcnt(14).
__global__ __launch_bounds__(256) void k_conv(
    const unsigned short* __restrict__ feat,   // (N+1) x 64 bf16
    const int* __restrict__ nbr,               // 27 x N
    const unsigned short* __restrict__ pw,     // packed weights (bf16 frag order)
    float* __restrict__ conv_out,              // N x 64 (pre-BN)
    float* __restrict__ partials)              // nblocks x 128 (sum | sumsq)
{
    __shared__ short ldsB[3][4096];            // 3 x 8 KB triple-buffered B tiles
    __shared__ float s_sum[64], s_sq[64];

    const int tid = threadIdx.x;
    const int l  = tid & 63;
    const int w  = tid >> 6;
    const int lr = l & 15;      // A row within 16 / C col within 16
    const int lg = l >> 4;      // cin-slice group / C row group
    const int rowbase = blockIdx.x * 128 + w * 32;
    const int r0 = rowbase + lr;
    const int r1 = r0 + 16;
    const int lane_cin = lg * 8;

    if (tid < 64) { s_sum[tid] = 0.f; s_sq[tid] = 0.f; }

    f32x4 acc[2][4] = {};
    const short8* pwv = reinterpret_cast<const short8*>(pw);
    const volatile int* vnbr = nbr;

    // idx pipeline regs: ia = idx[k+2] (arrived), ib = idx[k+3] (in flight)
    int ia0 = vnbr[r0],          ia1 = vnbr[r1];            // idx[0]
    int ib0 = vnbr[N_PTS + r0],  ib1 = vnbr[N_PTS + r1];    // idx[1]
    // A regs: ac = A(k) [row0s0,row0s1,row1s0,row1s1], an = A(k+1)
    short8 ac0 = {}, ac1 = {}, ac2 = {}, ac3 = {};
    short8 an0 = {}, an1 = {}, an2 = {}, an3 = {};

    #pragma unroll
    for (int kk = 0; kk < KOFF + 2; ++kk) {
        const int k = kk - 2;

        // ---- issue phase: exactly 8 vmcnt ops, identical shape every iter ----
        {   // glds B(clamp(k+1)) -> ldsB[(kk+2)%3], this wave's quarter (2 KB)
            int kg = k + 1; if (kg < 0) kg = 0; if (kg >= KOFF) kg = KOFF - 1;
            const short8* src = pwv + kg * 512 + w * 128;
            short* dst = &ldsB[(kk + 2) % 3][w * 1024];
            GLDS16(src + l,      dst);
            GLDS16(src + 64 + l, dst + 512);
        }
        short8 t0, t1, t2, t3;
        {   // gather A(k+2) using ia (= idx[clamp(k+2)], loaded 2 iters ago)
            const short8* g0 = reinterpret_cast<const short8*>(feat + ia0 * 64 + lane_cin);
            const short8* g1 = reinterpret_cast<const short8*>(feat + ia1 * 64 + lane_cin);
            t0 = g0[0]; t1 = g0[4]; t2 = g1[0]; t3 = g1[4];
        }
        int ic0, ic1;
        {   // idx[(k+4) mod 27] (wrap keeps addresses in-bounds; volatile stops CSE)
            const int ki = (k + 4) % KOFF;
            ic0 = vnbr[ki * N_PTS + r0];
            ic1 = vnbr[ki * N_PTS + r1];
        }
        __builtin_amdgcn_sched_barrier(0);   // pin all loads before the MFMA region

        if (k >= 0) {
            // wait for MY glds of B(k) (issued last iter; exactly 14 younger vmem ops),
            // then sync waves so all four quarters of B(k) are visible. Gathers for
            // A(k+1), A(k+2) stay in flight across the barrier.
            asm volatile("s_waitcnt vmcnt(14)" ::: "memory");
            __builtin_amdgcn_s_barrier();
            __builtin_amdgcn_sched_barrier(0);

            const short8* cb = reinterpret_cast<const short8*>(&ldsB[(kk + 1) % 3][0]);
            short8 b0 = cb[l];
            short8 b1 = cb[64 + l];
            short8 b2 = cb[128 + l];
            short8 b3 = cb[192 + l];
            short8 b4 = cb[256 + l];
            short8 b5 = cb[320 + l];
            short8 b6 = cb[384 + l];
            short8 b7 = cb[448 + l];
            acc[0][0] = __builtin_amdgcn_mfma_f32_16x16x32_bf16(ac0, b0, acc[0][0], 0, 0, 0);
            acc[1][0] = __builtin_amdgcn_mfma_f32_16x16x32_bf16(ac2, b0, acc[1][0], 0, 0, 0);
            acc[0][1] = __builtin_amdgcn_mfma_f32_16x16x32_bf16(ac0, b1, acc[0][1], 0, 0, 0);
            acc[1][1] = __builtin_amdgcn_mfma_f32_16x16x32_bf16(ac2, b1, acc[1][1], 0, 0, 0);
            acc[0][2] = __builtin_amdgcn_mfma_f32_16x16x32_bf16(ac0, b2, acc[0][2], 0, 0, 0);
            acc[1][2] = __builtin_amdgcn_mfma_f32_16x16x32_bf16(ac2, b2, acc[1][2], 0, 0, 0);
            acc[0][3] = __builtin_amdgcn_mfma_f32_16x16x32_bf16(ac0, b3, acc[0][3], 0, 0, 0);
            acc[1][3] = __builtin_amdgcn_mfma_f32_16x16x32_bf16(ac2, b3, acc[1][3], 0, 0, 0);
            acc[0][0] = __builtin_amdgcn_mfma_f32_16x16x32_bf16(ac1, b4, acc[0][0], 0, 0, 0);
            acc[1][0] = __builtin_amdgcn_mfma_f32_16x16x32_bf16(ac3, b4, acc[1][0], 0, 0, 0);
            acc[0][1] = __builtin_amdgcn_mfma_f32_16x16x32_bf16(ac1, b5, acc[0][1], 0, 0, 0);
            acc[1][1] = __builtin_amdgcn_mfma_f32_16x16x32_bf16(ac3, b5, acc[1][1], 0, 0, 0);
            acc[0][2] = __builtin_amdgcn_mfma_f32_16x16x32_bf16(ac1, b6, acc[0][2], 0, 0, 0);
            acc[1][2] = __builtin_amdgcn_mfma_f32_16x16x32_bf16(ac3, b6, acc[1][2], 0, 0, 0);
            acc[0][3] = __builtin_amdgcn_mfma_f32_16x16x32_bf16(ac1, b7, acc[0][3], 0, 0, 0);
            acc[1][3] = __builtin_amdgcn_mfma_f32_16x16x32_bf16(ac3, b7, acc[1][3], 0, 0, 0);
        }

        // rotate pipeline regs (SSA-renamed under full unroll)
        ia0 = ib0; ia1 = ib1; ib0 = ic0; ib1 = ic1;
        ac0 = an0; ac1 = an1; ac2 = an2; ac3 = an3;
        an0 = t0;  an1 = t1;  an2 = t2;  an3 = t3;
    }

    // ---- epilogue: store conv (f32) + per-channel partial stats ----
    const int orow_base = rowbase + lg * 4;   // C row = lg*4 + e (+ m*16)
    #pragma unroll
    for (int t = 0; t < 4; ++t) {
        const int c = t * 16 + lr;            // C col = lane&15
        float psum = 0.f, psq = 0.f;
        #pragma unroll
        for (int m = 0; m < 2; ++m) {
            #pragma unroll
            for (int e = 0; e < 4; ++e) {
                float v = acc[m][t][e];
                conv_out[(orow_base + m * 16 + e) * 64 + c] = v;
                psum += v; psq += v * v;
            }
        }
        atomicAdd(&s_sum[c], psum);
        atomicAdd(&s_sq[c], psq);
    }
    __syncthreads();
    if (tid < 64) {
        partials[blockIdx.x * 128 + tid]      = s_sum[tid];
        partials[blockIdx.x * 128 + 64 + tid] = s_sq[tid];
    }
}

// ---- S: reduce partials -> scale/shift per channel ----
__global__ void k_stats(const float* __restrict__ partials,
                        const float* __restrict__ gamma,
                        const float* __restrict__ beta,
                        float* __restrict__ ss, int nblocks) {
    __shared__ float s_red[2];
    const int c = blockIdx.x;
    const int tid = threadIdx.x;
    if (tid < 2) s_red[tid] = 0.f;
    __syncthreads();
    float sum = 0.f, sq = 0.f;
    for (int b = tid; b < nblocks; b += blockDim.x) {
        sum += partials[b * 128 + c];
        sq  += partials[b * 128 + 64 + c];
    }
    #pragma unroll
    for (int off = 32; off > 0; off >>= 1) {
        sum += __shfl_down(sum, off, 64);
        sq  += __shfl_down(sq,  off, 64);
    }
    if ((tid & 63) == 0) { atomicAdd(&s_red[0], sum); atomicAdd(&s_red[1], sq); }
    __syncthreads();
    if (tid == 0) {
        float mean  = s_red[0] / (float)N_PTS;
        float var   = s_red[1] / (float)N_PTS - mean * mean;
        float scale = gamma[c] * rsqrtf(var + EPS);
        ss[c]      = scale;
        ss[64 + c] = beta[c] - mean * scale;
    }
}

// ---- F: in-place BN affine + ReLU on d_out ----
__global__ void k_bnrelu(float* __restrict__ out, const float* __restrict__ ss) {
    int gid = blockIdx.x * blockDim.x + threadIdx.x;   // N*64/4 threads
    int base = gid * 4;
    int c0 = base & 63;
    f32x4 v  = *reinterpret_cast<f32x4*>(out + base);
    f32x4 sc = *reinterpret_cast<const f32x4*>(ss + c0);
    f32x4 sh = *reinterpret_cast<const f32x4*>(ss + 64 + c0);
    f32x4 r;
    #pragma unroll
    for (int j = 0; j < 4; ++j) r[j] = fmaxf(v[j] * sc[j] + sh[j], 0.f);
    *reinterpret_cast<f32x4*>(out + base) = r;
}

extern "C" void kernel_launch(void* const* d_in, const int* in_sizes, int n_in,
                              void* d_out, int out_size, void* d_ws, size_t ws_size,
                              hipStream_t stream) {
    const float* features = (const float*)d_in[0];
    const int*   nbr      = (const int*)d_in[1];
    const float* weight   = (const float*)d_in[2];
    const float* gamma    = (const float*)d_in[3];
    const float* beta     = (const float*)d_in[4];
    float* out = (float*)d_out;
    char* ws = (char*)d_ws;

    const size_t off_feat = 0;                                   // (N+1)*64 bf16
    const size_t off_pw   = 33554560;                            // 27*4096 bf16
    const size_t off_part = off_pw + 221184;                     // 2048*128 f32
    const size_t off_ss   = off_part + 1048576;                  // 128 f32
    unsigned short* feat16   = (unsigned short*)(ws + off_feat);
    unsigned short* pw       = (unsigned short*)(ws + off_pw);
    float*          partials = (float*)(ws + off_part);
    float*          ss       = (float*)(ws + off_ss);

    const int nblocks = N_PTS / 128;   // 2048

    k_packW<<<(KOFF * 4096 + 255) / 256, 256, 0, stream>>>(weight, pw);
    k_feat2bf16<<<((N_PTS + 1) * CIN / 4 + 255) / 256, 256, 0, stream>>>(features, feat16);
    k_conv<<<nblocks, 256, 0, stream>>>(feat16, nbr, pw, out, partials);
    k_stats<<<64, 256, 0, stream>>>(partials, gamma, beta, ss, nblocks);
    k_bnrelu<<<N_PTS * COUT / 4 / 256, 256, 0, stream>>>(out, ss);
}